// Round 7
// baseline (335.534 us; speedup 1.0000x reference)
//
#include <hip/hip_runtime.h>
#include <math.h>

#define S_LEN 3072
#define DIM 1536
#define NHEADS 16
#define HDIM 96
#define NPAIR 48

typedef __attribute__((ext_vector_type(8))) _Float16 half8;
typedef __attribute__((ext_vector_type(4))) _Float16 half4v;
typedef __attribute__((ext_vector_type(2))) _Float16 half2v;
typedef __attribute__((ext_vector_type(4))) float f32x4;

__device__ inline void gload16(const void* g, void* l) {
    __builtin_amdgcn_global_load_lds(
        (const __attribute__((address_space(1))) void*)g,
        (__attribute__((address_space(3))) void*)l, 16, 0, 0);
}

// Pinned 16B global load: volatile asm can't be sunk/rematerialized (R1/R3
// showed the compiler re-issues plain-load "prefetches" at their use point).
// Consumer must issue an explicit `s_waitcnt vmcnt(0)` (untracked by compiler).
__device__ inline uint4 gld128(const _Float16* p) {
    uint4 r;
    asm volatile("global_load_dwordx4 %0, %1, off"
                 : "=v"(r) : "v"(p));
    return r;
}

// ---------------- prep: fp32 -> fp16 elementwise ----------------
__global__ __launch_bounds__(256)
void convert_f32_f16(const float* __restrict__ src, _Float16* __restrict__ dst, int n4)
{
    int i = blockIdx.x * 256 + threadIdx.x;
    if (i < n4) {
        float4 v = *(const float4*)&src[(size_t)i * 4];
        half4v h = { (_Float16)v.x, (_Float16)v.y, (_Float16)v.z, (_Float16)v.w };
        *(half4v*)&dst[(size_t)i * 4] = h;
    }
}

// ---------------- prep: W[k][n] fp32 -> Wt[n][k] fp16 (64x64 LDS tiles) ----------------
__global__ __launch_bounds__(256)
void transpose_w(const float* __restrict__ w0, const float* __restrict__ w1,
                 const float* __restrict__ w2, const float* __restrict__ w3,
                 _Float16* __restrict__ wt)
{
    __shared__ _Float16 t[64][68];
    const int z = blockIdx.z;
    const float* W = (z == 0) ? w0 : (z == 1) ? w1 : (z == 2) ? w2 : w3;
    _Float16* O = wt + (size_t)z * DIM * DIM;
    const int k0 = blockIdx.y * 64, n0 = blockIdx.x * 64;
    const int tid = threadIdx.x;
    const int r = tid >> 4, c4 = (tid & 15) * 4;
#pragma unroll
    for (int g = 0; g < 4; g++) {
        int kk = r + g * 16;
        float4 v = *(const float4*)&W[(size_t)(k0 + kk) * DIM + n0 + c4];
        t[c4 + 0][kk] = (_Float16)v.x; t[c4 + 1][kk] = (_Float16)v.y;
        t[c4 + 2][kk] = (_Float16)v.z; t[c4 + 3][kk] = (_Float16)v.w;
    }
    __syncthreads();
    const int nr = tid >> 2, ks = (tid & 3) * 16;
#pragma unroll
    for (int s = 0; s < 4; s++)
        *(ushort4*)&O[(size_t)(n0 + nr) * DIM + k0 + ks + s * 4] =
            *(ushort4*)&t[nr][ks + s * 4];
}

// ---------------- fp16 MFMA GEMM, 256x256 tile, fused RoPE epilogue ----------------
// 512 threads / 8 waves (2x4); per-wave output 128x64 (8x4 16x16 frags).
// WHY 256^2: at 128^2 the QKV GEMM re-reads X 36x + W 24x = 680 MB of cache
// traffic (compute is only 17us of MFMA) -> cache-BW-bound. 256^2 halves
// traffic to 340 MB and gives exactly 1 block/CU (216 blocks, no tail).
// Staging: global_load_lds DOUBLE-buffered (R3/R4-proven pattern) - issue
// DMA for tile t+1 at top, vmcnt(0)+barrier at bottom -> HBM latency hides
// under the 64-MFMA compute phase instead of stalling at a commit point.
// QKV=true: q,k written [head][s][hd] with RoPE; v written TRANSPOSED [head][hd][s].
template<bool QKV>
__global__ __launch_bounds__(512, 1)
void gemm256_f16(const _Float16* __restrict__ X,
                 const _Float16* __restrict__ W0t, const _Float16* __restrict__ W1t,
                 const _Float16* __restrict__ W2t,
                 const float* __restrict__ B0, const float* __restrict__ B1,
                 const float* __restrict__ B2,
                 const float* __restrict__ fc, const float* __restrict__ fs,
                 void* __restrict__ outv)
{
    __shared__ __align__(16) _Float16 AsB[2][256 * 64];   // 64 KB
    __shared__ __align__(16) _Float16 BsB[2][256 * 64];   // 64 KB

    const int tid = threadIdx.x;
    const int w = tid >> 6, lane = tid & 63;
    const int ln = lane & 15, quad = lane >> 4;
    const int bz = blockIdx.z;
    const _Float16* Wt = W0t; const float* bias = B0;
    if (QKV) { if (bz == 1) { Wt = W1t; bias = B1; } else if (bz == 2) { Wt = W2t; bias = B2; } }
    const int m0 = blockIdx.y * 256, n0 = blockIdx.x * 256;
    const int wm = w >> 2, wn = w & 3;           // 2x4 wave grid
    const int row8 = lane >> 3, gch = (lane & 7) ^ row8;   // swizzled source chunk

    f32x4 acc[8][4];
#pragma unroll
    for (int i = 0; i < 8; i++)
#pragma unroll
        for (int j = 0; j < 4; j++) acc[i][j] = (f32x4){0.f, 0.f, 0.f, 0.f};

    // prologue: stage tile 0 into buf 0
#pragma unroll
    for (int j = 0; j < 4; j++) {
        const int r = w * 32 + j * 8;
        gload16(X  + (size_t)(m0 + r + row8) * DIM + 0 + gch * 8, &AsB[0][r * 64]);
        gload16(Wt + (size_t)(n0 + r + row8) * DIM + 0 + gch * 8, &BsB[0][r * 64]);
    }
    asm volatile("s_waitcnt vmcnt(0)");
    __syncthreads();

    const int NKT = DIM / 64;   // 24
    for (int kt = 0; kt < NKT; ++kt) {
        const int cur = kt & 1;
        // issue next K-tile's DMA into the other buffer (drained at loop-end vmcnt)
        if (kt + 1 < NKT) {
            const int k0 = (kt + 1) * 64;
#pragma unroll
            for (int j = 0; j < 4; j++) {
                const int r = w * 32 + j * 8;
                gload16(X  + (size_t)(m0 + r + row8) * DIM + k0 + gch * 8, &AsB[cur ^ 1][r * 64]);
                gload16(Wt + (size_t)(n0 + r + row8) * DIM + k0 + gch * 8, &BsB[cur ^ 1][r * 64]);
            }
            __builtin_amdgcn_sched_barrier(0);
        }

#pragma unroll
        for (int ks = 0; ks < 2; ks++) {
            const int s8 = (((ks * 4 + quad) ^ (ln & 7))) * 8;
            half8 a[8], b[4];
#pragma unroll
            for (int mt = 0; mt < 8; mt++)
                a[mt] = *(const half8*)&AsB[cur][(wm * 128 + mt * 16 + ln) * 64 + s8];
#pragma unroll
            for (int nt = 0; nt < 4; nt++)
                b[nt] = *(const half8*)&BsB[cur][(wn * 64 + nt * 16 + ln) * 64 + s8];
#pragma unroll
            for (int mt = 0; mt < 8; mt++)
#pragma unroll
                for (int nt = 0; nt < 4; nt++)
                    acc[mt][nt] = __builtin_amdgcn_mfma_f32_16x16x32_f16(
                        a[mt], b[nt], acc[mt][nt], 0, 0, 0);
        }

        asm volatile("s_waitcnt vmcnt(0)");   // next tile's DMA landed (issued ~600cy ago)
        __syncthreads();                      // all reads of buf[cur] done; DMA committed
    }

    // epilogue: C/D 16x16 layout col=ln, row=quad*4+reg
#pragma unroll
    for (int nt = 0; nt < 4; nt++) {
        int col = n0 + wn * 64 + nt * 16 + ln;
        float bv = bias[col];
        int head = col / HDIM, hd = col % HDIM;
        int jc = hd >> 1;                   // pair index; parity of hd == parity of ln
        bool isreal = (ln & 1) == 0;
#pragma unroll
        for (int mt = 0; mt < 8; mt++) {
            int row0 = m0 + wm * 128 + mt * 16 + quad * 4;
            if (QKV && bz == 2) {
                // V^T [head][hd][s]: 4 consecutive s values -> packed 8B store
                half4v p;
#pragma unroll
                for (int r = 0; r < 4; r++) p[r] = (_Float16)(acc[mt][nt][r] + bv);
                *(half4v*)&((_Float16*)outv)[(((size_t)2 * NHEADS + head) * HDIM + hd) * S_LEN + row0] = p;
            } else if (QKV) {
                // q/k with fused RoPE: pair partner lives in lane^1
                float v[4], vp[4];
#pragma unroll
                for (int r = 0; r < 4; r++) v[r] = acc[mt][nt][r] + bv;
#pragma unroll
                for (int r = 0; r < 4; r++) vp[r] = __shfl_xor(v[r], 1);
#pragma unroll
                for (int r = 0; r < 4; r++) {
                    int srow = row0 + r;
                    int pos = (jc < 32) ? (srow >> 6) : (srow & 63);
                    float c  = fc[pos * NPAIR + jc];
                    float sn = fs[pos * NPAIR + jc];
                    float xr = isreal ? v[r] : vp[r];
                    float xi = isreal ? vp[r] : v[r];
                    float rot = isreal ? (xr * c - xi * sn) : (xr * sn + xi * c);
                    float outval = (jc < 16) ? v[r] : rot;
                    ((_Float16*)outv)[(((size_t)bz * NHEADS + head) * S_LEN + srow) * HDIM + hd]
                        = (_Float16)outval;
                }
            } else {
#pragma unroll
                for (int r = 0; r < 4; r++)
                    ((float*)outv)[(size_t)(row0 + r) * DIM + col] = acc[mt][nt][r] + bv;
            }
        }
    }
}

// ---------------- MFMA fp16 flash attention (R4 kernel, fastest measured) ----------------
// 256 threads / 4 waves; wave-pair p owns KV half p (24 tiles).
//  * K: global_load_lds DOUBLE-buffered + mod-12 rotation swizzle. Prefetch
//    lives in the vmcnt counter -> unsinkable, zero VGPR.
//  * V: staged to LDS (Vt[96][72] XOR layout) through PINNED asm loads.
//  * Two barriers/tile, neither hiding global latency.
__global__ __launch_bounds__(256, 2)
void attn_mfma_kernel(const _Float16* __restrict__ qh, const _Float16* __restrict__ kh,
                      const _Float16* __restrict__ vtg, _Float16* __restrict__ aoh)
{
    __shared__ __align__(16) _Float16 Kb[2][2][64 * 96];   // [pair][buf], 48 KB
    __shared__ __align__(16) _Float16 Vt[2][96][72];       // [pair], 27 KB, XOR chunks

    const int tid  = threadIdx.x;      // 0..255
    const int wid  = tid >> 6;         // 0..3
    const int p    = wid >> 1;         // KV half this wave-pair owns
    const int wp   = wid & 1;          // wave within pair
    const int lane = tid & 63;
    const int ln   = lane & 15;
    const int quad = lane >> 4;
    const int h    = blockIdx.y;
    const int q0   = blockIdx.x * 64;
    const float scale_ = 0.10206207261596577f * 1.4426950408889634f;  // 1/sqrt(96) * log2(e)
    const int NT = (S_LEN / 2) / 64;   // 24 tiles per pair

    // Q fragments for 2 q-blocks (B-operand: col=ln=qrow, k=quad*8+j)
    half8 aq[2][3];
#pragma unroll
    for (int qs = 0; qs < 2; qs++) {
        const _Float16* qrow = qh + (((size_t)h * S_LEN) + q0 + (wp * 2 + qs) * 16 + ln) * HDIM;
#pragma unroll
        for (int kb = 0; kb < 3; kb++) {
            half8 a = *(const half8*)&qrow[kb * 32 + quad * 8];
            half8 v;
#pragma unroll
            for (int i = 0; i < 8; i++) v[i] = (_Float16)((float)a[i] * scale_);
            aq[qs][kb] = v;
        }
    }

    f32x4 o[2][6];
#pragma unroll
    for (int qs = 0; qs < 2; qs++)
#pragma unroll
        for (int dn = 0; dn < 6; dn++) o[qs][dn] = (f32x4){0.f, 0.f, 0.f, 0.f};
    float m_[2] = {-INFINITY, -INFINITY}, l_[2] = {0.f, 0.f};  // l_ per-lane (quad-partial)

    const char* kbase = (const char*)(kh + ((size_t)h * S_LEN + p * (S_LEN / 2)) * HDIM);

    // K staging precompute: wave-inst i covers phys chunks pc = i*128 + (tid&127);
    // phys (row r=pc/12, cc=pc%12) holds logical chunk (cc - r) mod 12.
    int koffb[6];
#pragma unroll
    for (int i = 0; i < 6; i++) {
        int pc = i * 128 + (tid & 127);
        int r  = pc / 12, c = pc - r * 12;
        int rm = r % 12;
        int cl = c - rm; if (cl < 0) cl += 12;
        koffb[i] = r * 192 + cl * 16;
    }
    // QK read: physical chunk cc' = (quad + ln + 4*(nb+kb)) % 12 = ksel[(nb+kb)%3]
    const int A0 = (quad + ln) % 12;
    int ksel[3];
    ksel[0] = A0 * 16;
    { int t1 = A0 + 4; if (t1 >= 12) t1 -= 12; ksel[1] = t1 * 16; }
    { int t2 = A0 + 8; if (t2 >= 12) t2 -= 12; ksel[2] = t2 * 16; }

    // V staging: pair-local thread tp -> d rows (tp>>3)+16u, chunk vc=tp&7;
    // XOR slot = vc ^ (vd0&7)
    const int tp = tid & 127;
    const int vd0 = tp >> 3, vc = tp & 7;
    const _Float16* vsrc0 = vtg + (size_t)h * HDIM * S_LEN + (size_t)vd0 * S_LEN
                          + p * (S_LEN / 2) + vc * 8;
    _Float16* vdst = &Vt[p][vd0][(vc ^ (vd0 & 7)) * 8];

    // ---- prologue: stage tile 0 (K via DMA, V via pinned regs) ----
#pragma unroll
    for (int i = 0; i < 6; i++)
        gload16(kbase + koffb[i], &Kb[p][0][i * 1024 + wp * 512]);
    uint4 vp0, vp1, vp2, vp3, vp4, vp5;
    vp0 = gld128(vsrc0 + 0 * 16 * S_LEN);
    vp1 = gld128(vsrc0 + 1 * 16 * S_LEN);
    vp2 = gld128(vsrc0 + 2 * 16 * S_LEN);
    vp3 = gld128(vsrc0 + 3 * 16 * S_LEN);
    vp4 = gld128(vsrc0 + 4 * 16 * S_LEN);
    vp5 = gld128(vsrc0 + 5 * 16 * S_LEN);
    asm volatile("s_waitcnt vmcnt(0)" ::: "memory");
    __builtin_amdgcn_sched_barrier(0);
    *(uint4*)(vdst + 0 * 16 * 72) = vp0;  *(uint4*)(vdst + 1 * 16 * 72) = vp1;
    *(uint4*)(vdst + 2 * 16 * 72) = vp2;  *(uint4*)(vdst + 3 * 16 * 72) = vp3;
    *(uint4*)(vdst + 4 * 16 * 72) = vp4;  *(uint4*)(vdst + 5 * 16 * 72) = vp5;
    __syncthreads();

    for (int kt = 0; kt < NT; ++kt) {
        const int cur = kt & 1;
        // issue next tile's K DMA (other buffer) and V pinned loads
        if (kt + 1 < NT) {
            const char* ks2 = kbase + (size_t)(kt + 1) * 12288;
#pragma unroll
            for (int i = 0; i < 6; i++)
                gload16(ks2 + koffb[i], &Kb[p][cur ^ 1][i * 1024 + wp * 512]);
            const _Float16* vs2 = vsrc0 + (kt + 1) * 64;
            vp0 = gld128(vs2 + 0 * 16 * S_LEN);
            vp1 = gld128(vs2 + 1 * 16 * S_LEN);
            vp2 = gld128(vs2 + 2 * 16 * S_LEN);
            vp3 = gld128(vs2 + 3 * 16 * S_LEN);
            vp4 = gld128(vs2 + 4 * 16 * S_LEN);
            vp5 = gld128(vs2 + 5 * 16 * S_LEN);
            __builtin_amdgcn_sched_barrier(0);
        }

        // S^T = K * Q^T; K-frags read ONCE, used for both q-blocks
        const char* Kc = (const char*)&Kb[p][cur][0];
        f32x4 s[2][4];
#pragma unroll
        for (int nb = 0; nb < 4; nb++) {
            const char* krow = Kc + (nb * 16 + ln) * 192;
            half8 ak0 = *(const half8*)(krow + ksel[(nb + 0) % 3]);
            half8 ak1 = *(const half8*)(krow + ksel[(nb + 1) % 3]);
            half8 ak2 = *(const half8*)(krow + ksel[(nb + 2) % 3]);
#pragma unroll
            for (int qs = 0; qs < 2; qs++) {
                f32x4 acc = (f32x4){0.f, 0.f, 0.f, 0.f};
                acc = __builtin_amdgcn_mfma_f32_16x16x32_f16(ak0, aq[qs][0], acc, 0, 0, 0);
                acc = __builtin_amdgcn_mfma_f32_16x16x32_f16(ak1, aq[qs][1], acc, 0, 0, 0);
                acc = __builtin_amdgcn_mfma_f32_16x16x32_f16(ak2, aq[qs][2], acc, 0, 0, 0);
                s[qs][nb] = acc;
            }
        }

        // online softmax in log2 domain; defer-max skips cross-lane work most tiles
        half4v ap[2][4];
#pragma unroll
        for (int qs = 0; qs < 2; qs++) {
            float ma = fmaxf(fmaxf(s[qs][0][0], s[qs][0][1]), fmaxf(s[qs][0][2], s[qs][0][3]));
            float mb = fmaxf(fmaxf(s[qs][1][0], s[qs][1][1]), fmaxf(s[qs][1][2], s[qs][1][3]));
            float mc = fmaxf(fmaxf(s[qs][2][0], s[qs][2][1]), fmaxf(s[qs][2][2], s[qs][2][3]));
            float md = fmaxf(fmaxf(s[qs][3][0], s[qs][3][1]), fmaxf(s[qs][3][2], s[qs][3][3]));
            float mx = fmaxf(fmaxf(ma, mb), fmaxf(mc, md));
            if (!__all(mx <= m_[qs] + 8.0f)) {       // rescale only when max really grew
                mx = fmaxf(mx, __shfl_xor(mx, 16));
                mx = fmaxf(mx, __shfl_xor(mx, 32));
                float mn = fmaxf(m_[qs], mx);
                float al = __builtin_amdgcn_exp2f(m_[qs] - mn);
                m_[qs] = mn;
                l_[qs] *= al;
#pragma unroll
                for (int dn = 0; dn < 6; dn++)
#pragma unroll
                    for (int r = 0; r < 4; r++) o[qs][dn][r] *= al;
            }
            float rs = 0.f;
            float mq = m_[qs];
#pragma unroll
            for (int nb = 0; nb < 4; nb++) {
                float p0 = __builtin_amdgcn_exp2f(s[qs][nb][0] - mq);
                float p1 = __builtin_amdgcn_exp2f(s[qs][nb][1] - mq);
                float p2 = __builtin_amdgcn_exp2f(s[qs][nb][2] - mq);
                float p3 = __builtin_amdgcn_exp2f(s[qs][nb][3] - mq);
                rs += (p0 + p1) + (p2 + p3);
                half4v pk = { (_Float16)p0, (_Float16)p1, (_Float16)p2, (_Float16)p3 };
                ap[qs][nb] = pk;                      // B-frag of 16x16x16: col=ln, k=quad*4+j
            }
            l_[qs] += rs;                             // cross-quad reduce deferred to epilogue
        }

        // PV with 16x16x16: A = V^T frag from LDS (XOR chunk layout)
#pragma unroll
        for (int nb = 0; nb < 4; nb++) {
            const int off = (((nb * 2 + (quad >> 1)) ^ (ln & 7)) * 8) + (quad & 1) * 4;
#pragma unroll
            for (int dn = 0; dn < 6; dn++) {
                half4v av = *(const half4v*)&Vt[p][dn * 16 + ln][off];
                o[0][dn] = __builtin_amdgcn_mfma_f32_16x16x16f16(av, ap[0][nb], o[0][dn], 0, 0, 0);
                o[1][dn] = __builtin_amdgcn_mfma_f32_16x16x16f16(av, ap[1][nb], o[1][dn], 0, 0, 0);
            }
        }

        __syncthreads();   // B: all PV reads of Vt done; K[t+1] DMA drained (tracked)
        asm volatile("s_waitcnt vmcnt(0)" ::: "memory");  // V[t+1] pinned regs arrived
        __builtin_amdgcn_sched_barrier(0);
        if (kt + 1 < NT) {
            *(uint4*)(vdst + 0 * 16 * 72) = vp0;  *(uint4*)(vdst + 1 * 16 * 72) = vp1;
            *(uint4*)(vdst + 2 * 16 * 72) = vp2;  *(uint4*)(vdst + 3 * 16 * 72) = vp3;
            *(uint4*)(vdst + 4 * 16 * 72) = vp4;  *(uint4*)(vdst + 5 * 16 * 72) = vp5;
        }
        __syncthreads();   // A: V[t+1] visible to pair partner
    }

    // ---- cross-pair merge through LDS (overlays Kb; all tile work is done) ----
    float lt[2];
#pragma unroll
    for (int qs = 0; qs < 2; qs++) {       // finish the deferred cross-quad l reduction
        float l = l_[qs];
        l += __shfl_xor(l, 16);
        l += __shfl_xor(l, 32);
        lt[qs] = l;
    }
    float*  scr = (float*)&Kb[0][0][0];                      // 64 x 100 f32 (25.6 KB)
    float2* mlb = (float2*)((char*)&Kb[0][0][0] + 26624);    // 64 x {m,l}
    if (p == 1) {
#pragma unroll
        for (int qs = 0; qs < 2; qs++) {
            int row = (wp * 2 + qs) * 16 + ln;
            if (quad == 0) mlb[row] = make_float2(m_[qs], lt[qs]);
#pragma unroll
            for (int dn = 0; dn < 6; dn++)
                *(f32x4*)&scr[row * 100 + dn * 16 + quad * 4] = o[qs][dn];
        }
    }
    __syncthreads();
    if (p == 0) {
#pragma unroll
        for (int qs = 0; qs < 2; qs++) {
            int row = (wp * 2 + qs) * 16 + ln;
            float2 ml1 = mlb[row];
            float mm = fmaxf(m_[qs], ml1.x);
            float a0 = __builtin_amdgcn_exp2f(m_[qs] - mm);
            float a1 = __builtin_amdgcn_exp2f(ml1.x - mm);
            float li = 1.0f / (lt[qs] * a0 + ml1.y * a1);
            const size_t rowbase = (size_t)(q0 + row) * DIM + h * HDIM;
#pragma unroll
            for (int dn = 0; dn < 6; dn++) {
                f32x4 o1 = *(const f32x4*)&scr[row * 100 + dn * 16 + quad * 4];
                half4v pk;
#pragma unroll
                for (int r = 0; r < 4; r++)
                    pk[r] = (_Float16)((o[qs][dn][r] * a0 + o1[r] * a1) * li);
                *(half4v*)&aoh[rowbase + dn * 16 + quad * 4] = pk;
            }
        }
    }
}

extern "C" void kernel_launch(void* const* d_in, const int* in_sizes, int n_in,
                              void* d_out, int out_size, void* d_ws, size_t ws_size,
                              hipStream_t stream) {
    const float* x  = (const float*)d_in[0];
    const float* wq = (const float*)d_in[1];
    const float* bq = (const float*)d_in[2];
    const float* wk = (const float*)d_in[3];
    const float* bk = (const float*)d_in[4];
    const float* wv = (const float*)d_in[5];
    const float* bv = (const float*)d_in[6];
    const float* wo = (const float*)d_in[7];
    const float* bo = (const float*)d_in[8];
    const float* fc = (const float*)d_in[9];
    const float* fs = (const float*)d_in[10];
    float* out = (float*)d_out;

    const size_t per  = (size_t)NHEADS * S_LEN * HDIM;   // 4,718,592
    const size_t dim2 = (size_t)DIM * DIM;               // 2,359,296
    _Float16* hws  = (_Float16*)d_ws;
    _Float16* qkvh = hws;                 // q,k fp16 [head][s][hd] (roped); v fp16 [head][hd][s]
    _Float16* qh   = qkvh;
    _Float16* kh   = qkvh + per;
    _Float16* vth  = qkvh + 2 * per;
    _Float16* xh   = hws + 3 * per;       // x fp16; later reused as ao fp16
    _Float16* wth  = hws + 4 * per;       // 4 transposed weights fp16

    convert_f32_f16<<<(int)((S_LEN * DIM / 4 + 255) / 256), 256, 0, stream>>>(
        x, xh, S_LEN * DIM / 4);
    transpose_w<<<dim3(DIM / 64, DIM / 64, 4), 256, 0, stream>>>(wq, wk, wv, wo, wth);

    // fused QKV projection + RoPE -> fp16 (256^2 tiles: 216 blocks, 1/CU)
    gemm256_f16<true><<<dim3(DIM / 256, S_LEN / 256, 3), 512, 0, stream>>>(
        xh, wth, wth + dim2, wth + 2 * dim2, bq, bk, bv, fc, fs, qkvh);
    attn_mfma_kernel<<<dim3(S_LEN / 64, NHEADS), 256, 0, stream>>>(qh, kh, vth, xh);
    gemm256_f16<false><<<dim3(DIM / 256, S_LEN / 256, 1), 512, 0, stream>>>(
        xh, wth + 3 * dim2, nullptr, nullptr, bo, nullptr, nullptr, fc, fs, out);
}

// Round 9
// 323.698 us; speedup vs baseline: 1.0366x; 1.0366x over previous
//
#include <hip/hip_runtime.h>
#include <math.h>

#define S_LEN 3072
#define DIM 1536
#define NHEADS 16
#define HDIM 96
#define NPAIR 48

typedef __attribute__((ext_vector_type(8))) _Float16 half8;
typedef __attribute__((ext_vector_type(4))) _Float16 half4v;
typedef __attribute__((ext_vector_type(2))) _Float16 half2v;
typedef __attribute__((ext_vector_type(4))) float f32x4;

__device__ inline void gload16(const void* g, void* l) {
    __builtin_amdgcn_global_load_lds(
        (const __attribute__((address_space(1))) void*)g,
        (__attribute__((address_space(3))) void*)l, 16, 0, 0);
}

// Pinned 16B global load: volatile asm can't be sunk/rematerialized (R1/R3
// showed the compiler re-issues plain-load "prefetches" at their use point).
// Consumer must issue an explicit `s_waitcnt vmcnt(0)` (untracked by compiler).
__device__ inline uint4 gld128(const _Float16* p) {
    uint4 r;
    asm volatile("global_load_dwordx4 %0, %1, off"
                 : "=v"(r) : "v"(p));
    return r;
}

// ---------------- prep: fp32 -> fp16 elementwise ----------------
__global__ __launch_bounds__(256)
void convert_f32_f16(const float* __restrict__ src, _Float16* __restrict__ dst, int n4)
{
    int i = blockIdx.x * 256 + threadIdx.x;
    if (i < n4) {
        float4 v = *(const float4*)&src[(size_t)i * 4];
        half4v h = { (_Float16)v.x, (_Float16)v.y, (_Float16)v.z, (_Float16)v.w };
        *(half4v*)&dst[(size_t)i * 4] = h;
    }
}

// ---------------- prep: W[k][n] fp32 -> Wt[n][k] fp16 (64x64 LDS tiles) ----------------
__global__ __launch_bounds__(256)
void transpose_w(const float* __restrict__ w0, const float* __restrict__ w1,
                 const float* __restrict__ w2, const float* __restrict__ w3,
                 _Float16* __restrict__ wt)
{
    __shared__ _Float16 t[64][68];
    const int z = blockIdx.z;
    const float* W = (z == 0) ? w0 : (z == 1) ? w1 : (z == 2) ? w2 : w3;
    _Float16* O = wt + (size_t)z * DIM * DIM;
    const int k0 = blockIdx.y * 64, n0 = blockIdx.x * 64;
    const int tid = threadIdx.x;
    const int r = tid >> 4, c4 = (tid & 15) * 4;
#pragma unroll
    for (int g = 0; g < 4; g++) {
        int kk = r + g * 16;
        float4 v = *(const float4*)&W[(size_t)(k0 + kk) * DIM + n0 + c4];
        t[c4 + 0][kk] = (_Float16)v.x; t[c4 + 1][kk] = (_Float16)v.y;
        t[c4 + 2][kk] = (_Float16)v.z; t[c4 + 3][kk] = (_Float16)v.w;
    }
    __syncthreads();
    const int nr = tid >> 2, ks = (tid & 3) * 16;
#pragma unroll
    for (int s = 0; s < 4; s++)
        *(ushort4*)&O[(size_t)(n0 + nr) * DIM + k0 + ks + s * 4] =
            *(ushort4*)&t[nr][ks + s * 4];
}

// ---------------- fp16 MFMA GEMM, counted-vmcnt pipeline + XCD swizzle ----------------
// R7 post-mortem: 256^2 w/ vmcnt(0)-per-step was neutral (GEMM+prep ~200us both at
// 128^2 and 256^2). Per-block compute is only ~620cy/K-step -> the ~190us GEMM phase
// can only be HBM latency/locality serialization: (a) 1 block/CU + all-wave lockstep
// vmcnt(0) drain = zero MLP; (b) round-robin block->XCD dispatch = zero L2 locality.
// Fixes: 2-deep counted-vmcnt pipeline with RAW s_barrier (never drain to 0 in the
// loop EXCEPT the final tile, whose loads have nothing behind them — R8 bug: counted
// wait passes immediately there, racing the DMA), and an XCD-aware 1D swizzle
// (nz-major/m-inner: each XCD's ~27 concurrent blocks share 3 B-panels, L2-fits).
// QKV=true: q,k written [head][s][hd] with RoPE; v written TRANSPOSED [head][hd][s].
template<bool QKV, int BM>
__global__ __launch_bounds__(512, 1)
void gemm_pipe_f16(const _Float16* __restrict__ X,
                   const _Float16* __restrict__ W0t, const _Float16* __restrict__ W1t,
                   const _Float16* __restrict__ W2t,
                   const float* __restrict__ B0, const float* __restrict__ B1,
                   const float* __restrict__ B2,
                   const float* __restrict__ fc, const float* __restrict__ fs,
                   void* __restrict__ outv)
{
    constexpr int MT = BM / 32;            // per-wave M-frags (256->8, 128->4)
    constexpr int AJ = BM / 64;            // A-staging insts per wave (4 / 2)
    __shared__ __align__(16) _Float16 As[2][BM * 64];    // 64 / 32 KB
    __shared__ __align__(16) _Float16 Bs[2][256 * 64];   // 64 KB

    const int tid = threadIdx.x;
    const int w = tid >> 6, lane = tid & 63;
    const int ln = lane & 15, quad = lane >> 4;
    const int row8 = lane >> 3, gch = (lane & 7) ^ row8;   // swizzled source chunk

    // XCD-aware swizzle: HW dispatches blockIdx round-robin across 8 XCDs;
    // remap so consecutive WORK ids land on one XCD (nwg % 8 == 0 for both grids).
    const int nwg = gridDim.x;
    const int wk = (blockIdx.x & 7) * (nwg >> 3) + (blockIdx.x >> 3);
    int m0, n0, bz;
    if (QKV) {                 // nwg=216: work = nz*12 + m, nz = bx + 6*bz
        const int m = wk % 12, nz = wk / 12;
        m0 = m * 256; n0 = (nz % 6) * 256; bz = nz / 6;
    } else {                   // nwg=144: work = n*24 + m
        m0 = (wk % 24) * 128; n0 = (wk / 24) * 256; bz = 0;
    }
    const _Float16* Wt = W0t; const float* bias = B0;
    if (QKV) { if (bz == 1) { Wt = W1t; bias = B1; } else if (bz == 2) { Wt = W2t; bias = B2; } }

    f32x4 acc[MT][4];
#pragma unroll
    for (int i = 0; i < MT; i++)
#pragma unroll
        for (int j = 0; j < 4; j++) acc[i][j] = (f32x4){0.f, 0.f, 0.f, 0.f};

    // stage one K-tile (k0) into buffer d: A = BM x 64, B = 256 x 64
    auto stage = [&](int k0, int d) {
#pragma unroll
        for (int j = 0; j < AJ; j++) {
            const int r = w * (BM / 8) + j * 8;
            gload16(X + (size_t)(m0 + r + row8) * DIM + k0 + gch * 8, &As[d][r * 64]);
        }
#pragma unroll
        for (int j = 0; j < 4; j++) {
            const int r = w * 32 + j * 8;
            gload16(Wt + (size_t)(n0 + r + row8) * DIM + k0 + gch * 8, &Bs[d][r * 64]);
        }
        __builtin_amdgcn_sched_barrier(0);
    };

    // prologue: tiles 0 and 1 in flight
    stage(0, 0);
    stage(64, 1);

    const int NKT = DIM / 64;   // 24
    for (int kt = 0; kt < NKT; ++kt) {
        const int cur = kt & 1;
        // wait for tile kt's loads only; tile kt+1's stay in flight across the
        // barrier. FINAL tile: nothing behind it -> counted wait passes with its
        // own loads still in flight, so drain fully (R8 race fix).
        if (kt == NKT - 1)       asm volatile("s_waitcnt vmcnt(0)" ::: "memory");
        else if constexpr (BM == 256) asm volatile("s_waitcnt vmcnt(8)" ::: "memory");
        else                     asm volatile("s_waitcnt vmcnt(6)" ::: "memory");
        __builtin_amdgcn_sched_barrier(0);
        __builtin_amdgcn_s_barrier();       // raw: no compiler vmcnt(0) drain
        __builtin_amdgcn_sched_barrier(0);

#pragma unroll
        for (int ks = 0; ks < 2; ks++) {
            const int s8 = (((ks * 4 + quad) ^ (ln & 7))) * 8;
            half8 a[MT], b[4];
#pragma unroll
            for (int mt = 0; mt < MT; mt++)
                a[mt] = *(const half8*)&As[cur][((w >> 2) * (BM / 2) + mt * 16 + ln) * 64 + s8];
#pragma unroll
            for (int nt = 0; nt < 4; nt++)
                b[nt] = *(const half8*)&Bs[cur][((w & 3) * 64 + nt * 16 + ln) * 64 + s8];
#pragma unroll
            for (int mt = 0; mt < MT; mt++)
#pragma unroll
                for (int nt = 0; nt < 4; nt++)
                    acc[mt][nt] = __builtin_amdgcn_mfma_f32_16x16x32_f16(
                        a[mt], b[nt], acc[mt][nt], 0, 0, 0);
        }

        __builtin_amdgcn_sched_barrier(0);
        __builtin_amdgcn_s_barrier();       // all reads of buf[cur] done block-wide
        __builtin_amdgcn_sched_barrier(0);
        if (kt + 2 < NKT) stage((kt + 2) * 64, cur);   // refill the buffer just freed
    }

    // epilogue: C/D 16x16 layout col=ln, row=quad*4+reg
    const int wm = w >> 2, wn = w & 3;
#pragma unroll
    for (int nt = 0; nt < 4; nt++) {
        int col = n0 + wn * 64 + nt * 16 + ln;
        float bv = bias[col];
        int head = col / HDIM, hd = col % HDIM;
        int jc = hd >> 1;                   // pair index; parity of hd == parity of ln
        bool isreal = (ln & 1) == 0;
#pragma unroll
        for (int mt = 0; mt < MT; mt++) {
            int row0 = m0 + wm * (BM / 2) + mt * 16 + quad * 4;
            if (QKV && bz == 2) {
                // V^T [head][hd][s]: 4 consecutive s values -> packed 8B store
                half4v p;
#pragma unroll
                for (int r = 0; r < 4; r++) p[r] = (_Float16)(acc[mt][nt][r] + bv);
                *(half4v*)&((_Float16*)outv)[(((size_t)2 * NHEADS + head) * HDIM + hd) * S_LEN + row0] = p;
            } else if (QKV) {
                // q/k with fused RoPE: pair partner lives in lane^1
                float v[4], vp[4];
#pragma unroll
                for (int r = 0; r < 4; r++) v[r] = acc[mt][nt][r] + bv;
#pragma unroll
                for (int r = 0; r < 4; r++) vp[r] = __shfl_xor(v[r], 1);
#pragma unroll
                for (int r = 0; r < 4; r++) {
                    int srow = row0 + r;
                    int pos = (jc < 32) ? (srow >> 6) : (srow & 63);
                    float c  = fc[pos * NPAIR + jc];
                    float sn = fs[pos * NPAIR + jc];
                    float xr = isreal ? v[r] : vp[r];
                    float xi = isreal ? vp[r] : v[r];
                    float rot = isreal ? (xr * c - xi * sn) : (xr * sn + xi * c);
                    float outval = (jc < 16) ? v[r] : rot;
                    ((_Float16*)outv)[(((size_t)bz * NHEADS + head) * S_LEN + srow) * HDIM + hd]
                        = (_Float16)outval;
                }
            } else {
#pragma unroll
                for (int r = 0; r < 4; r++)
                    ((float*)outv)[(size_t)(row0 + r) * DIM + col] = acc[mt][nt][r] + bv;
            }
        }
    }
}

// ---------------- MFMA fp16 flash attention (R4/R7 kernel, fastest measured) ----------------
// 256 threads / 4 waves; wave-pair p owns KV half p (24 tiles).
//  * K: global_load_lds DOUBLE-buffered + mod-12 rotation swizzle. Prefetch
//    lives in the vmcnt counter -> unsinkable, zero VGPR.
//  * V: staged to LDS (Vt[96][72] XOR layout) through PINNED asm loads.
__global__ __launch_bounds__(256, 2)
void attn_mfma_kernel(const _Float16* __restrict__ qh, const _Float16* __restrict__ kh,
                      const _Float16* __restrict__ vtg, _Float16* __restrict__ aoh)
{
    __shared__ __align__(16) _Float16 Kb[2][2][64 * 96];   // [pair][buf], 48 KB
    __shared__ __align__(16) _Float16 Vt[2][96][72];       // [pair], 27 KB, XOR chunks

    const int tid  = threadIdx.x;      // 0..255
    const int wid  = tid >> 6;         // 0..3
    const int p    = wid >> 1;         // KV half this wave-pair owns
    const int wp   = wid & 1;          // wave within pair
    const int lane = tid & 63;
    const int ln   = lane & 15;
    const int quad = lane >> 4;
    const int h    = blockIdx.y;
    const int q0   = blockIdx.x * 64;
    const float scale_ = 0.10206207261596577f * 1.4426950408889634f;  // 1/sqrt(96) * log2(e)
    const int NT = (S_LEN / 2) / 64;   // 24 tiles per pair

    // Q fragments for 2 q-blocks (B-operand: col=ln=qrow, k=quad*8+j)
    half8 aq[2][3];
#pragma unroll
    for (int qs = 0; qs < 2; qs++) {
        const _Float16* qrow = qh + (((size_t)h * S_LEN) + q0 + (wp * 2 + qs) * 16 + ln) * HDIM;
#pragma unroll
        for (int kb = 0; kb < 3; kb++) {
            half8 a = *(const half8*)&qrow[kb * 32 + quad * 8];
            half8 v;
#pragma unroll
            for (int i = 0; i < 8; i++) v[i] = (_Float16)((float)a[i] * scale_);
            aq[qs][kb] = v;
        }
    }

    f32x4 o[2][6];
#pragma unroll
    for (int qs = 0; qs < 2; qs++)
#pragma unroll
        for (int dn = 0; dn < 6; dn++) o[qs][dn] = (f32x4){0.f, 0.f, 0.f, 0.f};
    float m_[2] = {-INFINITY, -INFINITY}, l_[2] = {0.f, 0.f};  // l_ per-lane (quad-partial)

    const char* kbase = (const char*)(kh + ((size_t)h * S_LEN + p * (S_LEN / 2)) * HDIM);

    // K staging precompute: wave-inst i covers phys chunks pc = i*128 + (tid&127);
    // phys (row r=pc/12, cc=pc%12) holds logical chunk (cc - r) mod 12.
    int koffb[6];
#pragma unroll
    for (int i = 0; i < 6; i++) {
        int pc = i * 128 + (tid & 127);
        int r  = pc / 12, c = pc - r * 12;
        int rm = r % 12;
        int cl = c - rm; if (cl < 0) cl += 12;
        koffb[i] = r * 192 + cl * 16;
    }
    // QK read: physical chunk cc' = (quad + ln + 4*(nb+kb)) % 12 = ksel[(nb+kb)%3]
    const int A0 = (quad + ln) % 12;
    int ksel[3];
    ksel[0] = A0 * 16;
    { int t1 = A0 + 4; if (t1 >= 12) t1 -= 12; ksel[1] = t1 * 16; }
    { int t2 = A0 + 8; if (t2 >= 12) t2 -= 12; ksel[2] = t2 * 16; }

    // V staging: pair-local thread tp -> d rows (tp>>3)+16u, chunk vc=tp&7;
    // XOR slot = vc ^ (vd0&7)
    const int tp = tid & 127;
    const int vd0 = tp >> 3, vc = tp & 7;
    const _Float16* vsrc0 = vtg + (size_t)h * HDIM * S_LEN + (size_t)vd0 * S_LEN
                          + p * (S_LEN / 2) + vc * 8;
    _Float16* vdst = &Vt[p][vd0][(vc ^ (vd0 & 7)) * 8];

    // ---- prologue: stage tile 0 (K via DMA, V via pinned regs) ----
#pragma unroll
    for (int i = 0; i < 6; i++)
        gload16(kbase + koffb[i], &Kb[p][0][i * 1024 + wp * 512]);
    uint4 vp0, vp1, vp2, vp3, vp4, vp5;
    vp0 = gld128(vsrc0 + 0 * 16 * S_LEN);
    vp1 = gld128(vsrc0 + 1 * 16 * S_LEN);
    vp2 = gld128(vsrc0 + 2 * 16 * S_LEN);
    vp3 = gld128(vsrc0 + 3 * 16 * S_LEN);
    vp4 = gld128(vsrc0 + 4 * 16 * S_LEN);
    vp5 = gld128(vsrc0 + 5 * 16 * S_LEN);
    asm volatile("s_waitcnt vmcnt(0)" ::: "memory");
    __builtin_amdgcn_sched_barrier(0);
    *(uint4*)(vdst + 0 * 16 * 72) = vp0;  *(uint4*)(vdst + 1 * 16 * 72) = vp1;
    *(uint4*)(vdst + 2 * 16 * 72) = vp2;  *(uint4*)(vdst + 3 * 16 * 72) = vp3;
    *(uint4*)(vdst + 4 * 16 * 72) = vp4;  *(uint4*)(vdst + 5 * 16 * 72) = vp5;
    __syncthreads();

    for (int kt = 0; kt < NT; ++kt) {
        const int cur = kt & 1;
        // issue next tile's K DMA (other buffer) and V pinned loads
        if (kt + 1 < NT) {
            const char* ks2 = kbase + (size_t)(kt + 1) * 12288;
#pragma unroll
            for (int i = 0; i < 6; i++)
                gload16(ks2 + koffb[i], &Kb[p][cur ^ 1][i * 1024 + wp * 512]);
            const _Float16* vs2 = vsrc0 + (kt + 1) * 64;
            vp0 = gld128(vs2 + 0 * 16 * S_LEN);
            vp1 = gld128(vs2 + 1 * 16 * S_LEN);
            vp2 = gld128(vs2 + 2 * 16 * S_LEN);
            vp3 = gld128(vs2 + 3 * 16 * S_LEN);
            vp4 = gld128(vs2 + 4 * 16 * S_LEN);
            vp5 = gld128(vs2 + 5 * 16 * S_LEN);
            __builtin_amdgcn_sched_barrier(0);
        }

        // S^T = K * Q^T; K-frags read ONCE, used for both q-blocks
        const char* Kc = (const char*)&Kb[p][cur][0];
        f32x4 s[2][4];
#pragma unroll
        for (int nb = 0; nb < 4; nb++) {
            const char* krow = Kc + (nb * 16 + ln) * 192;
            half8 ak0 = *(const half8*)(krow + ksel[(nb + 0) % 3]);
            half8 ak1 = *(const half8*)(krow + ksel[(nb + 1) % 3]);
            half8 ak2 = *(const half8*)(krow + ksel[(nb + 2) % 3]);
#pragma unroll
            for (int qs = 0; qs < 2; qs++) {
                f32x4 acc = (f32x4){0.f, 0.f, 0.f, 0.f};
                acc = __builtin_amdgcn_mfma_f32_16x16x32_f16(ak0, aq[qs][0], acc, 0, 0, 0);
                acc = __builtin_amdgcn_mfma_f32_16x16x32_f16(ak1, aq[qs][1], acc, 0, 0, 0);
                acc = __builtin_amdgcn_mfma_f32_16x16x32_f16(ak2, aq[qs][2], acc, 0, 0, 0);
                s[qs][nb] = acc;
            }
        }

        // online softmax in log2 domain; defer-max skips cross-lane work most tiles
        half4v ap[2][4];
#pragma unroll
        for (int qs = 0; qs < 2; qs++) {
            float ma = fmaxf(fmaxf(s[qs][0][0], s[qs][0][1]), fmaxf(s[qs][0][2], s[qs][0][3]));
            float mb = fmaxf(fmaxf(s[qs][1][0], s[qs][1][1]), fmaxf(s[qs][1][2], s[qs][1][3]));
            float mc = fmaxf(fmaxf(s[qs][2][0], s[qs][2][1]), fmaxf(s[qs][2][2], s[qs][2][3]));
            float md = fmaxf(fmaxf(s[qs][3][0], s[qs][3][1]), fmaxf(s[qs][3][2], s[qs][3][3]));
            float mx = fmaxf(fmaxf(ma, mb), fmaxf(mc, md));
            if (!__all(mx <= m_[qs] + 8.0f)) {       // rescale only when max really grew
                mx = fmaxf(mx, __shfl_xor(mx, 16));
                mx = fmaxf(mx, __shfl_xor(mx, 32));
                float mn = fmaxf(m_[qs], mx);
                float al = __builtin_amdgcn_exp2f(m_[qs] - mn);
                m_[qs] = mn;
                l_[qs] *= al;
#pragma unroll
                for (int dn = 0; dn < 6; dn++)
#pragma unroll
                    for (int r = 0; r < 4; r++) o[qs][dn][r] *= al;
            }
            float rs = 0.f;
            float mq = m_[qs];
#pragma unroll
            for (int nb = 0; nb < 4; nb++) {
                float p0 = __builtin_amdgcn_exp2f(s[qs][nb][0] - mq);
                float p1 = __builtin_amdgcn_exp2f(s[qs][nb][1] - mq);
                float p2 = __builtin_amdgcn_exp2f(s[qs][nb][2] - mq);
                float p3 = __builtin_amdgcn_exp2f(s[qs][nb][3] - mq);
                rs += (p0 + p1) + (p2 + p3);
                half4v pk = { (_Float16)p0, (_Float16)p1, (_Float16)p2, (_Float16)p3 };
                ap[qs][nb] = pk;                      // B-frag of 16x16x16: col=ln, k=quad*4+j
            }
            l_[qs] += rs;                             // cross-quad reduce deferred to epilogue
        }

        // PV with 16x16x16: A = V^T frag from LDS (XOR chunk layout)
#pragma unroll
        for (int nb = 0; nb < 4; nb++) {
            const int off = (((nb * 2 + (quad >> 1)) ^ (ln & 7)) * 8) + (quad & 1) * 4;
#pragma unroll
            for (int dn = 0; dn < 6; dn++) {
                half4v av = *(const half4v*)&Vt[p][dn * 16 + ln][off];
                o[0][dn] = __builtin_amdgcn_mfma_f32_16x16x16f16(av, ap[0][nb], o[0][dn], 0, 0, 0);
                o[1][dn] = __builtin_amdgcn_mfma_f32_16x16x16f16(av, ap[1][nb], o[1][dn], 0, 0, 0);
            }
        }

        __syncthreads();   // B: all PV reads of Vt done; K[t+1] DMA drained (tracked)
        asm volatile("s_waitcnt vmcnt(0)" ::: "memory");  // V[t+1] pinned regs arrived
        __builtin_amdgcn_sched_barrier(0);
        if (kt + 1 < NT) {
            *(uint4*)(vdst + 0 * 16 * 72) = vp0;  *(uint4*)(vdst + 1 * 16 * 72) = vp1;
            *(uint4*)(vdst + 2 * 16 * 72) = vp2;  *(uint4*)(vdst + 3 * 16 * 72) = vp3;
            *(uint4*)(vdst + 4 * 16 * 72) = vp4;  *(uint4*)(vdst + 5 * 16 * 72) = vp5;
        }
        __syncthreads();   // A: V[t+1] visible to pair partner
    }

    // ---- cross-pair merge through LDS (overlays Kb; all tile work is done) ----
    float lt[2];
#pragma unroll
    for (int qs = 0; qs < 2; qs++) {       // finish the deferred cross-quad l reduction
        float l = l_[qs];
        l += __shfl_xor(l, 16);
        l += __shfl_xor(l, 32);
        lt[qs] = l;
    }
    float*  scr = (float*)&Kb[0][0][0];                      // 64 x 100 f32 (25.6 KB)
    float2* mlb = (float2*)((char*)&Kb[0][0][0] + 26624);    // 64 x {m,l}
    if (p == 1) {
#pragma unroll
        for (int qs = 0; qs < 2; qs++) {
            int row = (wp * 2 + qs) * 16 + ln;
            if (quad == 0) mlb[row] = make_float2(m_[qs], lt[qs]);
#pragma unroll
            for (int dn = 0; dn < 6; dn++)
                *(f32x4*)&scr[row * 100 + dn * 16 + quad * 4] = o[qs][dn];
        }
    }
    __syncthreads();
    if (p == 0) {
#pragma unroll
        for (int qs = 0; qs < 2; qs++) {
            int row = (wp * 2 + qs) * 16 + ln;
            float2 ml1 = mlb[row];
            float mm = fmaxf(m_[qs], ml1.x);
            float a0 = __builtin_amdgcn_exp2f(m_[qs] - mm);
            float a1 = __builtin_amdgcn_exp2f(ml1.x - mm);
            float li = 1.0f / (lt[qs] * a0 + ml1.y * a1);
            const size_t rowbase = (size_t)(q0 + row) * DIM + h * HDIM;
#pragma unroll
            for (int dn = 0; dn < 6; dn++) {
                f32x4 o1 = *(const f32x4*)&scr[row * 100 + dn * 16 + quad * 4];
                half4v pk;
#pragma unroll
                for (int r = 0; r < 4; r++)
                    pk[r] = (_Float16)((o[qs][dn][r] * a0 + o1[r] * a1) * li);
                *(half4v*)&aoh[rowbase + dn * 16 + quad * 4] = pk;
            }
        }
    }
}

extern "C" void kernel_launch(void* const* d_in, const int* in_sizes, int n_in,
                              void* d_out, int out_size, void* d_ws, size_t ws_size,
                              hipStream_t stream) {
    const float* x  = (const float*)d_in[0];
    const float* wq = (const float*)d_in[1];
    const float* bq = (const float*)d_in[2];
    const float* wk = (const float*)d_in[3];
    const float* bk = (const float*)d_in[4];
    const float* wv = (const float*)d_in[5];
    const float* bv = (const float*)d_in[6];
    const float* wo = (const float*)d_in[7];
    const float* bo = (const float*)d_in[8];
    const float* fc = (const float*)d_in[9];
    const float* fs = (const float*)d_in[10];
    float* out = (float*)d_out;

    const size_t per  = (size_t)NHEADS * S_LEN * HDIM;   // 4,718,592
    const size_t dim2 = (size_t)DIM * DIM;               // 2,359,296
    _Float16* hws  = (_Float16*)d_ws;
    _Float16* qkvh = hws;                 // q,k fp16 [head][s][hd] (roped); v fp16 [head][hd][s]
    _Float16* qh   = qkvh;
    _Float16* kh   = qkvh + per;
    _Float16* vth  = qkvh + 2 * per;
    _Float16* xh   = hws + 3 * per;       // x fp16; later reused as ao fp16
    _Float16* wth  = hws + 4 * per;       // 4 transposed weights fp16

    convert_f32_f16<<<(int)((S_LEN * DIM / 4 + 255) / 256), 256, 0, stream>>>(
        x, xh, S_LEN * DIM / 4);
    transpose_w<<<dim3(DIM / 64, DIM / 64, 4), 256, 0, stream>>>(wq, wk, wv, wo, wth);

    // fused QKV projection + RoPE -> fp16 (216 blocks, XCD-swizzled, pipelined)
    gemm_pipe_f16<true, 256><<<216, 512, 0, stream>>>(
        xh, wth, wth + dim2, wth + 2 * dim2, bq, bk, bv, fc, fs, qkvh);
    attn_mfma_kernel<<<dim3(S_LEN / 64, NHEADS), 256, 0, stream>>>(qh, kh, vth, xh);
    gemm_pipe_f16<false, 128><<<144, 512, 0, stream>>>(
        xh, wth + 3 * dim2, nullptr, nullptr, bo, nullptr, nullptr, fc, fs, out);
}

// Round 11
// 312.612 us; speedup vs baseline: 1.0733x; 1.0355x over previous
//
#include <hip/hip_runtime.h>
#include <math.h>

#define S_LEN 3072
#define DIM 1536
#define NHEADS 16
#define HDIM 96
#define NPAIR 48

typedef __attribute__((ext_vector_type(8))) _Float16 half8;
typedef __attribute__((ext_vector_type(4))) _Float16 half4v;
typedef __attribute__((ext_vector_type(2))) _Float16 half2v;
typedef __attribute__((ext_vector_type(4))) float f32x4;

__device__ inline void gload16(const void* g, void* l) {
    __builtin_amdgcn_global_load_lds(
        (const __attribute__((address_space(1))) void*)g,
        (__attribute__((address_space(3))) void*)l, 16, 0, 0);
}

// Pinned 16B global load: volatile asm can't be sunk/rematerialized (R1/R3
// showed the compiler re-issues plain-load "prefetches" at their use point).
// Consumer must issue an explicit `s_waitcnt vmcnt(0)` (untracked by compiler).
__device__ inline uint4 gld128(const _Float16* p) {
    uint4 r;
    asm volatile("global_load_dwordx4 %0, %1, off"
                 : "=v"(r) : "v"(p));
    return r;
}

// ---------------- prep: fp32 -> fp16 elementwise ----------------
__global__ __launch_bounds__(256)
void convert_f32_f16(const float* __restrict__ src, _Float16* __restrict__ dst, int n4)
{
    int i = blockIdx.x * 256 + threadIdx.x;
    if (i < n4) {
        float4 v = *(const float4*)&src[(size_t)i * 4];
        half4v h = { (_Float16)v.x, (_Float16)v.y, (_Float16)v.z, (_Float16)v.w };
        *(half4v*)&dst[(size_t)i * 4] = h;
    }
}

// ---------------- prep: W[k][n] fp32 -> Wt[n][k] fp16 (64x64 LDS tiles) ----------------
__global__ __launch_bounds__(256)
void transpose_w(const float* __restrict__ w0, const float* __restrict__ w1,
                 const float* __restrict__ w2, const float* __restrict__ w3,
                 _Float16* __restrict__ wt)
{
    __shared__ _Float16 t[64][68];
    const int z = blockIdx.z;
    const float* W = (z == 0) ? w0 : (z == 1) ? w1 : (z == 2) ? w2 : w3;
    _Float16* O = wt + (size_t)z * DIM * DIM;
    const int k0 = blockIdx.y * 64, n0 = blockIdx.x * 64;
    const int tid = threadIdx.x;
    const int r = tid >> 4, c4 = (tid & 15) * 4;
#pragma unroll
    for (int g = 0; g < 4; g++) {
        int kk = r + g * 16;
        float4 v = *(const float4*)&W[(size_t)(k0 + kk) * DIM + n0 + c4];
        t[c4 + 0][kk] = (_Float16)v.x; t[c4 + 1][kk] = (_Float16)v.y;
        t[c4 + 2][kk] = (_Float16)v.z; t[c4 + 3][kk] = (_Float16)v.w;
    }
    __syncthreads();
    const int nr = tid >> 2, ks = (tid & 3) * 16;
#pragma unroll
    for (int s = 0; s < 4; s++)
        *(ushort4*)&O[(size_t)(n0 + nr) * DIM + k0 + ks + s * 4] =
            *(ushort4*)&t[nr][ks + s * 4];
}

// ---------------- fp16 MFMA GEMM, counted-vmcnt pipeline + XCD swizzle (R9) ----------------
template<bool QKV, int BM>
__global__ __launch_bounds__(512, 1)
void gemm_pipe_f16(const _Float16* __restrict__ X,
                   const _Float16* __restrict__ W0t, const _Float16* __restrict__ W1t,
                   const _Float16* __restrict__ W2t,
                   const float* __restrict__ B0, const float* __restrict__ B1,
                   const float* __restrict__ B2,
                   const float* __restrict__ fc, const float* __restrict__ fs,
                   void* __restrict__ outv)
{
    constexpr int MT = BM / 32;            // per-wave M-frags (256->8, 128->4)
    constexpr int AJ = BM / 64;            // A-staging insts per wave (4 / 2)
    __shared__ __align__(16) _Float16 As[2][BM * 64];    // 64 / 32 KB
    __shared__ __align__(16) _Float16 Bs[2][256 * 64];   // 64 KB

    const int tid = threadIdx.x;
    const int w = tid >> 6, lane = tid & 63;
    const int ln = lane & 15, quad = lane >> 4;
    const int row8 = lane >> 3, gch = (lane & 7) ^ row8;   // swizzled source chunk

    // XCD-aware swizzle: consecutive WORK ids land on one XCD (nwg % 8 == 0).
    const int nwg = gridDim.x;
    const int wk = (blockIdx.x & 7) * (nwg >> 3) + (blockIdx.x >> 3);
    int m0, n0, bz;
    if (QKV) {                 // nwg=216: work = nz*12 + m, nz = bx + 6*bz
        const int m = wk % 12, nz = wk / 12;
        m0 = m * 256; n0 = (nz % 6) * 256; bz = nz / 6;
    } else {                   // nwg=144: work = n*24 + m
        m0 = (wk % 24) * 128; n0 = (wk / 24) * 256; bz = 0;
    }
    const _Float16* Wt = W0t; const float* bias = B0;
    if (QKV) { if (bz == 1) { Wt = W1t; bias = B1; } else if (bz == 2) { Wt = W2t; bias = B2; } }

    f32x4 acc[MT][4];
#pragma unroll
    for (int i = 0; i < MT; i++)
#pragma unroll
        for (int j = 0; j < 4; j++) acc[i][j] = (f32x4){0.f, 0.f, 0.f, 0.f};

    // stage one K-tile (k0) into buffer d: A = BM x 64, B = 256 x 64
    auto stage = [&](int k0, int d) {
#pragma unroll
        for (int j = 0; j < AJ; j++) {
            const int r = w * (BM / 8) + j * 8;
            gload16(X + (size_t)(m0 + r + row8) * DIM + k0 + gch * 8, &As[d][r * 64]);
        }
#pragma unroll
        for (int j = 0; j < 4; j++) {
            const int r = w * 32 + j * 8;
            gload16(Wt + (size_t)(n0 + r + row8) * DIM + k0 + gch * 8, &Bs[d][r * 64]);
        }
        __builtin_amdgcn_sched_barrier(0);
    };

    // prologue: tiles 0 and 1 in flight
    stage(0, 0);
    stage(64, 1);

    const int NKT = DIM / 64;   // 24
    for (int kt = 0; kt < NKT; ++kt) {
        const int cur = kt & 1;
        // wait for tile kt's loads only; tile kt+1's stay in flight across the
        // barrier. FINAL tile: nothing behind it -> drain fully (R8 race fix).
        if (kt == NKT - 1)       asm volatile("s_waitcnt vmcnt(0)" ::: "memory");
        else if constexpr (BM == 256) asm volatile("s_waitcnt vmcnt(8)" ::: "memory");
        else                     asm volatile("s_waitcnt vmcnt(6)" ::: "memory");
        __builtin_amdgcn_sched_barrier(0);
        __builtin_amdgcn_s_barrier();       // raw: no compiler vmcnt(0) drain
        __builtin_amdgcn_sched_barrier(0);

#pragma unroll
        for (int ks = 0; ks < 2; ks++) {
            const int s8 = (((ks * 4 + quad) ^ (ln & 7))) * 8;
            half8 a[MT], b[4];
#pragma unroll
            for (int mt = 0; mt < MT; mt++)
                a[mt] = *(const half8*)&As[cur][((w >> 2) * (BM / 2) + mt * 16 + ln) * 64 + s8];
#pragma unroll
            for (int nt = 0; nt < 4; nt++)
                b[nt] = *(const half8*)&Bs[cur][((w & 3) * 64 + nt * 16 + ln) * 64 + s8];
#pragma unroll
            for (int mt = 0; mt < MT; mt++)
#pragma unroll
                for (int nt = 0; nt < 4; nt++)
                    acc[mt][nt] = __builtin_amdgcn_mfma_f32_16x16x32_f16(
                        a[mt], b[nt], acc[mt][nt], 0, 0, 0);
        }

        __builtin_amdgcn_sched_barrier(0);
        __builtin_amdgcn_s_barrier();       // all reads of buf[cur] done block-wide
        __builtin_amdgcn_sched_barrier(0);
        if (kt + 2 < NKT) stage((kt + 2) * 64, cur);   // refill the buffer just freed
    }

    // epilogue: C/D 16x16 layout col=ln, row=quad*4+reg
    const int wm = w >> 2, wn = w & 3;
#pragma unroll
    for (int nt = 0; nt < 4; nt++) {
        int col = n0 + wn * 64 + nt * 16 + ln;
        float bv = bias[col];
        int head = col / HDIM, hd = col % HDIM;
        int jc = hd >> 1;                   // pair index; parity of hd == parity of ln
        bool isreal = (ln & 1) == 0;
#pragma unroll
        for (int mt = 0; mt < MT; mt++) {
            int row0 = m0 + wm * (BM / 2) + mt * 16 + quad * 4;
            if (QKV && bz == 2) {
                // V^T [head][hd][s]: 4 consecutive s values -> packed 8B store
                half4v p;
#pragma unroll
                for (int r = 0; r < 4; r++) p[r] = (_Float16)(acc[mt][nt][r] + bv);
                *(half4v*)&((_Float16*)outv)[(((size_t)2 * NHEADS + head) * HDIM + hd) * S_LEN + row0] = p;
            } else if (QKV) {
                // q/k with fused RoPE: pair partner lives in lane^1
                float v[4], vp[4];
#pragma unroll
                for (int r = 0; r < 4; r++) v[r] = acc[mt][nt][r] + bv;
#pragma unroll
                for (int r = 0; r < 4; r++) vp[r] = __shfl_xor(v[r], 1);
#pragma unroll
                for (int r = 0; r < 4; r++) {
                    int srow = row0 + r;
                    int pos = (jc < 32) ? (srow >> 6) : (srow & 63);
                    float c  = fc[pos * NPAIR + jc];
                    float sn = fs[pos * NPAIR + jc];
                    float xr = isreal ? v[r] : vp[r];
                    float xi = isreal ? vp[r] : v[r];
                    float rot = isreal ? (xr * c - xi * sn) : (xr * sn + xi * c);
                    float outval = (jc < 16) ? v[r] : rot;
                    ((_Float16*)outv)[(((size_t)bz * NHEADS + head) * S_LEN + srow) * HDIM + hd]
                        = (_Float16)outval;
                }
            } else {
#pragma unroll
                for (int r = 0; r < 4; r++)
                    ((float*)outv)[(size_t)(row0 + r) * DIM + col] = acc[mt][nt][r] + bv;
            }
        }
    }
}

// ---------------- MFMA fp16 flash attention, 3 blocks/CU target ----------------
// R9 ran 768 blocks at 2 blocks/CU = 512 resident + 256-block half-empty tail
// round. K drops its LDS double buffer and prefetches through the SAME pinned-asm
// path as V. LDS 52,224B -> 3 blocks/CU (LDS-limited), 768 = 256x3 -> one round,
// zero tail. R10 crashed with __launch_bounds__(256,3); the forced ~168-VGPR cap
// could spill in-flight asm-load results (untracked by waitcnt -> UB). This round:
// (256,2) — no forced cap; natural VGPR (est ~116-140, R4 measured 92 for the
// near-identical set) stays under the 168 needed for 3 blocks. If VGPR_Count >168
// in the profile, occupancy fell back to 2 blocks and the result reads neutral.
__global__ __launch_bounds__(256, 2)
void attn_mfma_kernel(const _Float16* __restrict__ qh, const _Float16* __restrict__ kh,
                      const _Float16* __restrict__ vtg, _Float16* __restrict__ aoh)
{
    __shared__ __align__(16) _Float16 Kb[2][64 * 96];   // [pair], 24 KB, mod-12 rotation
    __shared__ __align__(16) _Float16 Vt[2][96][72];    // [pair], 27 KB, XOR chunks

    const int tid  = threadIdx.x;      // 0..255
    const int wid  = tid >> 6;         // 0..3
    const int p    = wid >> 1;         // KV half this wave-pair owns
    const int wp   = wid & 1;          // wave within pair
    const int lane = tid & 63;
    const int ln   = lane & 15;
    const int quad = lane >> 4;
    const int h    = blockIdx.y;
    const int q0   = blockIdx.x * 64;
    const float scale_ = 0.10206207261596577f * 1.4426950408889634f;  // 1/sqrt(96) * log2(e)
    const int NT = (S_LEN / 2) / 64;   // 24 tiles per pair

    // Q fragments for 2 q-blocks (B-operand: col=ln=qrow, k=quad*8+j)
    half8 aq[2][3];
#pragma unroll
    for (int qs = 0; qs < 2; qs++) {
        const _Float16* qrow = qh + (((size_t)h * S_LEN) + q0 + (wp * 2 + qs) * 16 + ln) * HDIM;
#pragma unroll
        for (int kb = 0; kb < 3; kb++) {
            half8 a = *(const half8*)&qrow[kb * 32 + quad * 8];
            half8 v;
#pragma unroll
            for (int i = 0; i < 8; i++) v[i] = (_Float16)((float)a[i] * scale_);
            aq[qs][kb] = v;
        }
    }

    f32x4 o[2][6];
#pragma unroll
    for (int qs = 0; qs < 2; qs++)
#pragma unroll
        for (int dn = 0; dn < 6; dn++) o[qs][dn] = (f32x4){0.f, 0.f, 0.f, 0.f};
    float m_[2] = {-INFINITY, -INFINITY}, l_[2] = {0.f, 0.f};  // l_ per-lane (quad-partial)

    const char* kbase = (const char*)(kh + ((size_t)h * S_LEN + p * (S_LEN / 2)) * HDIM);
    const int tp = tid & 127;          // pair-local thread id

    // K staging precompute: inst i covers phys chunks pc = i*128 + tp; phys
    // (row r=pc/12, cc=pc%12) holds logical chunk (cc - r) mod 12 -> source offset.
    int koffb[6];
#pragma unroll
    for (int i = 0; i < 6; i++) {
        int pc = i * 128 + tp;
        int r  = pc / 12, c = pc - r * 12;
        int rm = r % 12;
        int cl = c - rm; if (cl < 0) cl += 12;
        koffb[i] = r * 192 + cl * 16;
    }
    _Float16* kdst = &Kb[p][tp * 8];   // phys chunk pc at LDS elem pc*8 (byte pc*16)
    // QK read: physical chunk cc' = (quad + ln + 4*(nb+kb)) % 12 = ksel[(nb+kb)%3]
    const int A0 = (quad + ln) % 12;
    int ksel[3];
    ksel[0] = A0 * 16;
    { int t1 = A0 + 4; if (t1 >= 12) t1 -= 12; ksel[1] = t1 * 16; }
    { int t2 = A0 + 8; if (t2 >= 12) t2 -= 12; ksel[2] = t2 * 16; }

    // V staging: pair-local thread tp -> d rows (tp>>3)+16u, chunk vc=tp&7;
    // XOR slot = vc ^ (vd0&7)
    const int vd0 = tp >> 3, vc = tp & 7;
    const _Float16* vsrc0 = vtg + (size_t)h * HDIM * S_LEN + (size_t)vd0 * S_LEN
                          + p * (S_LEN / 2) + vc * 8;
    _Float16* vdst = &Vt[p][vd0][(vc ^ (vd0 & 7)) * 8];

    // ---- prologue: stage tile 0 (K and V via pinned regs) ----
    uint4 kp0, kp1, kp2, kp3, kp4, kp5, vp0, vp1, vp2, vp3, vp4, vp5;
    kp0 = gld128((const _Float16*)(kbase + koffb[0]));
    kp1 = gld128((const _Float16*)(kbase + koffb[1]));
    kp2 = gld128((const _Float16*)(kbase + koffb[2]));
    kp3 = gld128((const _Float16*)(kbase + koffb[3]));
    kp4 = gld128((const _Float16*)(kbase + koffb[4]));
    kp5 = gld128((const _Float16*)(kbase + koffb[5]));
    vp0 = gld128(vsrc0 + 0 * 16 * S_LEN);
    vp1 = gld128(vsrc0 + 1 * 16 * S_LEN);
    vp2 = gld128(vsrc0 + 2 * 16 * S_LEN);
    vp3 = gld128(vsrc0 + 3 * 16 * S_LEN);
    vp4 = gld128(vsrc0 + 4 * 16 * S_LEN);
    vp5 = gld128(vsrc0 + 5 * 16 * S_LEN);
    asm volatile("s_waitcnt vmcnt(0)" ::: "memory");
    __builtin_amdgcn_sched_barrier(0);
    *(uint4*)(kdst + 0 * 1024) = kp0;  *(uint4*)(kdst + 1 * 1024) = kp1;
    *(uint4*)(kdst + 2 * 1024) = kp2;  *(uint4*)(kdst + 3 * 1024) = kp3;
    *(uint4*)(kdst + 4 * 1024) = kp4;  *(uint4*)(kdst + 5 * 1024) = kp5;
    *(uint4*)(vdst + 0 * 16 * 72) = vp0;  *(uint4*)(vdst + 1 * 16 * 72) = vp1;
    *(uint4*)(vdst + 2 * 16 * 72) = vp2;  *(uint4*)(vdst + 3 * 16 * 72) = vp3;
    *(uint4*)(vdst + 4 * 16 * 72) = vp4;  *(uint4*)(vdst + 5 * 16 * 72) = vp5;
    __syncthreads();

    for (int kt = 0; kt < NT; ++kt) {
        // issue next tile's K and V pinned loads; latency covered by QK+softmax+PV
        if (kt + 1 < NT) {
            const char* ks2 = kbase + (size_t)(kt + 1) * 12288;
            kp0 = gld128((const _Float16*)(ks2 + koffb[0]));
            kp1 = gld128((const _Float16*)(ks2 + koffb[1]));
            kp2 = gld128((const _Float16*)(ks2 + koffb[2]));
            kp3 = gld128((const _Float16*)(ks2 + koffb[3]));
            kp4 = gld128((const _Float16*)(ks2 + koffb[4]));
            kp5 = gld128((const _Float16*)(ks2 + koffb[5]));
            const _Float16* vs2 = vsrc0 + (kt + 1) * 64;
            vp0 = gld128(vs2 + 0 * 16 * S_LEN);
            vp1 = gld128(vs2 + 1 * 16 * S_LEN);
            vp2 = gld128(vs2 + 2 * 16 * S_LEN);
            vp3 = gld128(vs2 + 3 * 16 * S_LEN);
            vp4 = gld128(vs2 + 4 * 16 * S_LEN);
            vp5 = gld128(vs2 + 5 * 16 * S_LEN);
            __builtin_amdgcn_sched_barrier(0);
        }

        // S^T = K * Q^T; K-frags read ONCE, used for both q-blocks
        const char* Kc = (const char*)&Kb[p][0];
        f32x4 s[2][4];
#pragma unroll
        for (int nb = 0; nb < 4; nb++) {
            const char* krow = Kc + (nb * 16 + ln) * 192;
            half8 ak0 = *(const half8*)(krow + ksel[(nb + 0) % 3]);
            half8 ak1 = *(const half8*)(krow + ksel[(nb + 1) % 3]);
            half8 ak2 = *(const half8*)(krow + ksel[(nb + 2) % 3]);
#pragma unroll
            for (int qs = 0; qs < 2; qs++) {
                f32x4 acc = (f32x4){0.f, 0.f, 0.f, 0.f};
                acc = __builtin_amdgcn_mfma_f32_16x16x32_f16(ak0, aq[qs][0], acc, 0, 0, 0);
                acc = __builtin_amdgcn_mfma_f32_16x16x32_f16(ak1, aq[qs][1], acc, 0, 0, 0);
                acc = __builtin_amdgcn_mfma_f32_16x16x32_f16(ak2, aq[qs][2], acc, 0, 0, 0);
                s[qs][nb] = acc;
            }
        }

        // online softmax in log2 domain; defer-max skips cross-lane work most tiles
        half4v ap[2][4];
#pragma unroll
        for (int qs = 0; qs < 2; qs++) {
            float ma = fmaxf(fmaxf(s[qs][0][0], s[qs][0][1]), fmaxf(s[qs][0][2], s[qs][0][3]));
            float mb = fmaxf(fmaxf(s[qs][1][0], s[qs][1][1]), fmaxf(s[qs][1][2], s[qs][1][3]));
            float mc = fmaxf(fmaxf(s[qs][2][0], s[qs][2][1]), fmaxf(s[qs][2][2], s[qs][2][3]));
            float md = fmaxf(fmaxf(s[qs][3][0], s[qs][3][1]), fmaxf(s[qs][3][2], s[qs][3][3]));
            float mx = fmaxf(fmaxf(ma, mb), fmaxf(mc, md));
            if (!__all(mx <= m_[qs] + 8.0f)) {       // rescale only when max really grew
                mx = fmaxf(mx, __shfl_xor(mx, 16));
                mx = fmaxf(mx, __shfl_xor(mx, 32));
                float mn = fmaxf(m_[qs], mx);
                float al = __builtin_amdgcn_exp2f(m_[qs] - mn);
                m_[qs] = mn;
                l_[qs] *= al;
#pragma unroll
                for (int dn = 0; dn < 6; dn++)
#pragma unroll
                    for (int r = 0; r < 4; r++) o[qs][dn][r] *= al;
            }
            float rs = 0.f;
            float mq = m_[qs];
#pragma unroll
            for (int nb = 0; nb < 4; nb++) {
                float p0 = __builtin_amdgcn_exp2f(s[qs][nb][0] - mq);
                float p1 = __builtin_amdgcn_exp2f(s[qs][nb][1] - mq);
                float p2 = __builtin_amdgcn_exp2f(s[qs][nb][2] - mq);
                float p3 = __builtin_amdgcn_exp2f(s[qs][nb][3] - mq);
                rs += (p0 + p1) + (p2 + p3);
                half4v pk = { (_Float16)p0, (_Float16)p1, (_Float16)p2, (_Float16)p3 };
                ap[qs][nb] = pk;                      // B-frag of 16x16x16: col=ln, k=quad*4+j
            }
            l_[qs] += rs;                             // cross-quad reduce deferred to epilogue
        }

        // PV with 16x16x16: A = V^T frag from LDS (XOR chunk layout)
#pragma unroll
        for (int nb = 0; nb < 4; nb++) {
            const int off = (((nb * 2 + (quad >> 1)) ^ (ln & 7)) * 8) + (quad & 1) * 4;
#pragma unroll
            for (int dn = 0; dn < 6; dn++) {
                half4v av = *(const half4v*)&Vt[p][dn * 16 + ln][off];
                o[0][dn] = __builtin_amdgcn_mfma_f32_16x16x16f16(av, ap[0][nb], o[0][dn], 0, 0, 0);
                o[1][dn] = __builtin_amdgcn_mfma_f32_16x16x16f16(av, ap[1][nb], o[1][dn], 0, 0, 0);
            }
        }

        __syncthreads();   // B: all QK/PV reads of Kb/Vt done
        asm volatile("s_waitcnt vmcnt(0)" ::: "memory");  // K/V[t+1] pinned regs arrived
        __builtin_amdgcn_sched_barrier(0);
        if (kt + 1 < NT) {
            *(uint4*)(kdst + 0 * 1024) = kp0;  *(uint4*)(kdst + 1 * 1024) = kp1;
            *(uint4*)(kdst + 2 * 1024) = kp2;  *(uint4*)(kdst + 3 * 1024) = kp3;
            *(uint4*)(kdst + 4 * 1024) = kp4;  *(uint4*)(kdst + 5 * 1024) = kp5;
            *(uint4*)(vdst + 0 * 16 * 72) = vp0;  *(uint4*)(vdst + 1 * 16 * 72) = vp1;
            *(uint4*)(vdst + 2 * 16 * 72) = vp2;  *(uint4*)(vdst + 3 * 16 * 72) = vp3;
            *(uint4*)(vdst + 4 * 16 * 72) = vp4;  *(uint4*)(vdst + 5 * 16 * 72) = vp5;
        }
        __syncthreads();   // A: K/V[t+1] visible to pair partner
    }

    // ---- cross-pair merge through LDS (scratch overlays Vt; all reads done) ----
    float lt[2];
#pragma unroll
    for (int qs = 0; qs < 2; qs++) {       // finish the deferred cross-quad l reduction
        float l = l_[qs];
        l += __shfl_xor(l, 16);
        l += __shfl_xor(l, 32);
        lt[qs] = l;
    }
    float*  scr = (float*)&Vt[0][0][0];                      // 64 x 100 f32 (25.6 KB)
    float2* mlb = (float2*)((char*)&Vt[0][0][0] + 26624);    // 64 x {m,l}
    if (p == 1) {
#pragma unroll
        for (int qs = 0; qs < 2; qs++) {
            int row = (wp * 2 + qs) * 16 + ln;
            if (quad == 0) mlb[row] = make_float2(m_[qs], lt[qs]);
#pragma unroll
            for (int dn = 0; dn < 6; dn++)
                *(f32x4*)&scr[row * 100 + dn * 16 + quad * 4] = o[qs][dn];
        }
    }
    __syncthreads();
    if (p == 0) {
#pragma unroll
        for (int qs = 0; qs < 2; qs++) {
            int row = (wp * 2 + qs) * 16 + ln;
            float2 ml1 = mlb[row];
            float mm = fmaxf(m_[qs], ml1.x);
            float a0 = __builtin_amdgcn_exp2f(m_[qs] - mm);
            float a1 = __builtin_amdgcn_exp2f(ml1.x - mm);
            float li = 1.0f / (lt[qs] * a0 + ml1.y * a1);
            const size_t rowbase = (size_t)(q0 + row) * DIM + h * HDIM;
#pragma unroll
            for (int dn = 0; dn < 6; dn++) {
                f32x4 o1 = *(const f32x4*)&scr[row * 100 + dn * 16 + quad * 4];
                half4v pk;
#pragma unroll
                for (int r = 0; r < 4; r++)
                    pk[r] = (_Float16)((o[qs][dn][r] * a0 + o1[r] * a1) * li);
                *(half4v*)&aoh[rowbase + dn * 16 + quad * 4] = pk;
            }
        }
    }
}

extern "C" void kernel_launch(void* const* d_in, const int* in_sizes, int n_in,
                              void* d_out, int out_size, void* d_ws, size_t ws_size,
                              hipStream_t stream) {
    const float* x  = (const float*)d_in[0];
    const float* wq = (const float*)d_in[1];
    const float* bq = (const float*)d_in[2];
    const float* wk = (const float*)d_in[3];
    const float* bk = (const float*)d_in[4];
    const float* wv = (const float*)d_in[5];
    const float* bv = (const float*)d_in[6];
    const float* wo = (const float*)d_in[7];
    const float* bo = (const float*)d_in[8];
    const float* fc = (const float*)d_in[9];
    const float* fs = (const float*)d_in[10];
    float* out = (float*)d_out;

    const size_t per  = (size_t)NHEADS * S_LEN * HDIM;   // 4,718,592
    const size_t dim2 = (size_t)DIM * DIM;               // 2,359,296
    _Float16* hws  = (_Float16*)d_ws;
    _Float16* qkvh = hws;                 // q,k fp16 [head][s][hd] (roped); v fp16 [head][hd][s]
    _Float16* qh   = qkvh;
    _Float16* kh   = qkvh + per;
    _Float16* vth  = qkvh + 2 * per;
    _Float16* xh   = hws + 3 * per;       // x fp16; later reused as ao fp16
    _Float16* wth  = hws + 4 * per;       // 4 transposed weights fp16

    convert_f32_f16<<<(int)((S_LEN * DIM / 4 + 255) / 256), 256, 0, stream>>>(
        x, xh, S_LEN * DIM / 4);
    transpose_w<<<dim3(DIM / 64, DIM / 64, 4), 256, 0, stream>>>(wq, wk, wv, wo, wth);

    // fused QKV projection + RoPE -> fp16 (216 blocks, XCD-swizzled, pipelined)
    gemm_pipe_f16<true, 256><<<216, 512, 0, stream>>>(
        xh, wth, wth + dim2, wth + 2 * dim2, bq, bk, bv, fc, fs, qkvh);
    attn_mfma_kernel<<<dim3(S_LEN / 64, NHEADS), 256, 0, stream>>>(qh, kh, vth, xh);
    gemm_pipe_f16<false, 128><<<144, 512, 0, stream>>>(
        xh, wth + 3 * dim2, nullptr, nullptr, bo, nullptr, nullptr, fc, fs, out);
}